// Round 11
// baseline (523.666 us; speedup 1.0000x reference)
//
#include <hip/hip_runtime.h>

typedef unsigned short u16;
typedef unsigned int u32;
typedef __attribute__((ext_vector_type(8))) short bf16x8;
typedef __attribute__((ext_vector_type(4))) float f32x4;
typedef __attribute__((ext_vector_type(4))) int i32x4;
typedef __attribute__((ext_vector_type(2))) unsigned int u32x2;

// T=4096 tokens, D=1024, F=4096, E=8, K=2. Inputs fp32.
// gemm1 consumes fp32 w1/w3 DIRECTLY (no prep). w2 still pre-converted (tiled bf16) under gemm1.
// ws: xb(8M) | H(64M) | (unused 128M) | w2t(64M) | wa/alist/cnt

__device__ __forceinline__ u16 f2bf(float f) {
  u32 u = __builtin_bit_cast(u32, f);
  u += 0x7fffu + ((u >> 16) & 1u);
  return (u16)(u >> 16);
}
__device__ __forceinline__ u32 pack2(u16 a, u16 b) { return (u32)a | ((u32)b << 16); }

__device__ __forceinline__ u32 cvt2(float a, float b) { return pack2(f2bf(a), f2bf(b)); }

// Build a B-fragment (8 k-consecutive bf16) from fp32 LDS column pointer (row stride 64 dwords).
__device__ __forceinline__ bf16x8 bfrag(const float* bp) {
  i32x4 v;
  v[0] = (int)cvt2(bp[0],   bp[64]);
  v[1] = (int)cvt2(bp[128], bp[192]);
  v[2] = (int)cvt2(bp[256], bp[320]);
  v[3] = (int)cvt2(bp[384], bp[448]);
  return __builtin_bit_cast(bf16x8, v);
}

// XOR-swizzled LDS byte address for [row][64 bf16] GEMM tiles (128B rows); 16B-unit swizzle.
__device__ __forceinline__ char* lds_swz(void* base, int row, int byteInRow) {
  return (char*)base + (((row << 7) + byteInRow) ^ ((row & 7) << 4));
}

// async global->LDS, 16B per lane; LDS dest = wave-uniform base + lane*16, global src per-lane.
#define GLL16(g, l) __builtin_amdgcn_global_load_lds( \
    (const __attribute__((address_space(1))) void*)(g), \
    (__attribute__((address_space(3))) void*)(l), 16, 0, 0)

// ---------------- router ----------------
__global__ __launch_bounds__(256) void router_k(
    const float* __restrict__ x, const float* __restrict__ gw,
    float* __restrict__ probs, u16* __restrict__ xb,
    float* __restrict__ wa, int* __restrict__ alist, int* __restrict__ cnt)
{
  const int t = blockIdx.x;
  const int tid = threadIdx.x;
  f32x4 xv = ((const f32x4*)(x + (size_t)t * 1024))[tid];
  u32x2 hb;
  hb[0] = pack2(f2bf(xv[0]), f2bf(xv[1]));
  hb[1] = pack2(f2bf(xv[2]), f2bf(xv[3]));
  *(u32x2*)(xb + (size_t)t * 1024 + tid * 4) = hb;

  float acc[8];
#pragma unroll
  for (int e = 0; e < 8; ++e) acc[e] = 0.f;
  const float* g = gw + tid * 32;
#pragma unroll
  for (int j = 0; j < 4; ++j)
#pragma unroll
    for (int e = 0; e < 8; ++e) acc[e] = fmaf(xv[j], g[j * 8 + e], acc[e]);

#pragma unroll
  for (int e = 0; e < 8; ++e)
    for (int off = 32; off > 0; off >>= 1) acc[e] += __shfl_down(acc[e], off);

  __shared__ float red[32];
  const int lane = tid & 63, wid = tid >> 6;
  if (lane == 0) {
#pragma unroll
    for (int e = 0; e < 8; ++e) red[wid * 8 + e] = acc[e];
  }
  __syncthreads();
  if (tid == 0) {
    float p[8]; float mx = -1e30f;
#pragma unroll
    for (int e = 0; e < 8; ++e) { p[e] = red[e] + red[8 + e] + red[16 + e] + red[24 + e]; mx = fmaxf(mx, p[e]); }
    float s = 0.f;
#pragma unroll
    for (int e = 0; e < 8; ++e) { p[e] = __expf(p[e] - mx); s += p[e]; }
    float inv = 1.f / s;
#pragma unroll
    for (int e = 0; e < 8; ++e) { p[e] *= inv; probs[(size_t)t * 8 + e] = p[e]; }
    int i0 = 0;
#pragma unroll
    for (int e = 1; e < 8; ++e) if (p[e] > p[i0]) i0 = e;
    int i1 = (i0 == 0) ? 1 : 0;
#pragma unroll
    for (int e = 0; e < 8; ++e) if (e != i0 && p[e] > p[i1]) i1 = e;
    float s2 = p[i0] + p[i1];
    int pos0 = atomicAdd(&cnt[i0], 1); alist[i0 * 4096 + pos0] = t * 2;
    int pos1 = atomicAdd(&cnt[i1], 1); alist[i1 * 4096 + pos1] = t * 2 + 1;
    wa[t * 2]     = p[i0] / s2;
    wa[t * 2 + 1] = p[i1] / s2;
  }
}

// ---------------- launch B: gemm1 (fp32-B direct) + w2 tiled prep overlaid ----------------
// bx<64: gemm1 N-tile bx; bx 64..79: w2 prep (64k x 128n per block).
__global__ __launch_bounds__(256, 2) void gemm1w2_k(
    const u16* __restrict__ xb, const float* __restrict__ w1, const float* __restrict__ w3,
    const int* __restrict__ alist, const int* __restrict__ cnt, u16* __restrict__ H,
    const float* __restrict__ w2, u16* __restrict__ w2t)
{
  __shared__ __align__(16) char smem[49664];
  const int e = blockIdx.z;
  const int bx = blockIdx.x;
  const int tid = threadIdx.x;

  if (bx >= 64) {
    // ---- w2 prep (R9-proven): [4096f][1024d] fp32 -> tiled bf16 [e][nt16][kt64][64n][64k]
    const int slot = ((bx - 64) * 32 + blockIdx.y) * 8 + e;  // 0..4095
    const int e2  = slot >> 9;
    const int ktb = (slot >> 3) & 63;
    const int nc  = slot & 7;
    const float* src = w2 + (size_t)e2 * 4194304 + (size_t)(ktb * 64) * 1024 + nc * 128;
    float* lds = (float*)smem;                 // [64][128] fp32 = 32 KB

    const int w = tid >> 6, l = tid & 63;
#pragma unroll
    for (int q = 0; q < 8; ++q) {
      const int r2 = w * 8 + q;
      GLL16(src + (size_t)(2 * r2 + (l >> 5)) * 1024 + (l & 31) * 4, lds + r2 * 256);
    }
    asm volatile("s_waitcnt vmcnt(0)" ::: "memory");
    __syncthreads();

    const int s = (tid >> 6) & 1, n = tid & 63, kh2 = tid >> 7;
    const int cc = s * 64 + n;
    u32 p[16];
#pragma unroll
    for (int i = 0; i < 16; ++i) {
      float a = lds[(kh2 * 32 + 2 * i) * 128 + cc];
      float b = lds[(kh2 * 32 + 2 * i + 1) * 128 + cc];
      p[i] = pack2(f2bf(a), f2bf(b));
    }
    u16* dp = w2t + (((size_t)e2 * 16 + nc * 2 + s) * 64 + ktb) * 4096 + n * 64 + kh2 * 32;
#pragma unroll
    for (int k = 0; k < 4; ++k)
      *(i32x4*)(dp + k * 8) = *(const i32x4*)&p[k * 4];
    return;
  }

  // ---- gemm1: H = silu(x@w1)*(x@w3); A bf16 LDS (swizzled), B fp32 LDS (rotated columns)
  u16*  As   = (u16*)smem;               // [128*64] bf16 = 16384B
  int*  rowid = (int*)(smem + 16384);    // 512B
  float* Bs32 = (float*)(smem + 16896);  // [2 mats][64k][64n] fp32 = 32768B

  const int mc = cnt[e];
  const int m0 = blockIdx.y * 128;
  if (m0 >= mc) return;
  const int n0 = bx * 64;

  if (tid < 128) rowid[tid] = (m0 + tid < mc) ? alist[e * 4096 + m0 + tid] : -1;
  __syncthreads();

  const int l = tid & 63, w = tid >> 6;

  // A staging pointers (unchanged, R3-proven)
  const u16* aps[4]; u16* ald[4];
#pragma unroll
  for (int q = 0; q < 4; ++q) {
    int ra = 32 * w + 8 * q + (l >> 3);
    int id = rowid[ra];
    aps[q] = xb + (size_t)(id < 0 ? 0 : (id >> 1)) * 1024 + ((l & 7) ^ (ra & 7)) * 8;
    ald[q] = As + (32 * w + 8 * q) * 64;
  }

  // B staging: wave w stages mat (w>>1), k-half (w&1). 8 GLL16/wave, rotated source chunks.
  const float* wsel = (w >> 1) ? w3 : w1;
  const int kh = w & 1, rl = l >> 4, c0 = l & 15;
  const float* bsrc = wsel + (size_t)e * 4194304 + (size_t)(kh * 32 + rl) * 4096 + n0;
  const int ofA = c0 * 4;
  const int ofB = ((c0 + 4) & 15) * 4;
  float* bdst = Bs32 + (w >> 1) * 4096 + kh * 2048;

  const int wm = (w >> 1) * 64, wn = (w & 1) * 32;
  const int l15 = l & 15, lg = l >> 4;
  const int gR = lg & 1;
  const int cp0 = ((wn + l15) + 48 * gR) & 63;
  const int cp1 = ((wn + 16 + l15) + 48 * gR) & 63;

  f32x4 acc1[4][2], acc3[4][2];
  const f32x4 zf = {0.f, 0.f, 0.f, 0.f};
#pragma unroll
  for (int mi = 0; mi < 4; ++mi) { acc1[mi][0] = zf; acc1[mi][1] = zf; acc3[mi][0] = zf; acc3[mi][1] = zf; }

  for (int kt = 0; kt < 16; ++kt) {
#pragma unroll
    for (int q = 0; q < 4; ++q) GLL16(aps[q] + kt * 64, ald[q]);
    const float* bk = bsrc + (size_t)kt * 262144;     // +64 rows
#pragma unroll
    for (int q = 0; q < 8; ++q)
      GLL16(bk + q * 16384 + (((q >> 1) & 1) ? ofB : ofA), bdst + q * 256);
    __syncthreads();

#pragma unroll
    for (int ks = 0; ks < 2; ++ks) {
      const int kbA = ks * 64 + lg * 16;              // byte offset within A row
      bf16x8 af[4];
#pragma unroll
      for (int mi = 0; mi < 4; ++mi)
        af[mi] = *(const bf16x8*)lds_swz(As, wm + mi * 16 + l15, kbA);
      const float* b0 = Bs32 + ks * 2048 + lg * 512;  // k = ks*32 + lg*8, row stride 64
#pragma unroll
      for (int ni = 0; ni < 2; ++ni) {
        const int cp = ni ? cp1 : cp0;
        bf16x8 b1 = bfrag(b0 + cp);
        bf16x8 b3 = bfrag(b0 + 4096 + cp);
#pragma unroll
        for (int mi = 0; mi < 4; ++mi) {
          acc1[mi][ni] = __builtin_amdgcn_mfma_f32_16x16x32_bf16(af[mi], b1, acc1[mi][ni], 0, 0, 0);
          acc3[mi][ni] = __builtin_amdgcn_mfma_f32_16x16x32_bf16(af[mi], b3, acc3[mi][ni], 0, 0, 0);
        }
      }
    }
    __syncthreads();
  }

#pragma unroll
  for (int mi = 0; mi < 4; ++mi) {
    const int rb = wm + mi * 16 + lg * 4;
#pragma unroll
    for (int ni = 0; ni < 2; ++ni) {
      const int col = n0 + wn + ni * 16 + l15;
      f32x4 c1 = acc1[mi][ni], c3 = acc3[mi][ni];
#pragma unroll
      for (int j = 0; j < 4; ++j) {
        int id = rowid[rb + j];
        if (id >= 0) {
          float a = c1[j];
          float h = (a / (1.f + __expf(-a))) * c3[j];
          H[(size_t)id * 4096 + col] = f2bf(h);
        }
      }
    }
  }
}

// ---------------- gemm2: out[token] += wa * (H @ w2), split-K=2, fused combine, tiled B (R9-proven) ----------------
__global__ __launch_bounds__(256, 2) void gemm2_k(
    const u16* __restrict__ H, const u16* __restrict__ w2t,
    const int* __restrict__ alist, const int* __restrict__ cnt,
    const float* __restrict__ wa, float* __restrict__ out)
{
  const int e = blockIdx.z;
  const int mc = cnt[e];
  const int yy = blockIdx.y;
  const int kh = yy & 1;
  const int m0 = (yy >> 1) * 128;
  if (m0 >= mc) return;
  const int n0 = blockIdx.x * 128;
  const int tid = threadIdx.x;

  __shared__ u16 As[128 * 64];
  __shared__ u16 Bs[128 * 64];
  __shared__ int rowid[128];
  __shared__ float rw[128];

  if (tid < 128) {
    int id = (m0 + tid < mc) ? alist[e * 4096 + m0 + tid] : -1;
    rowid[tid] = id;
    rw[tid] = (id >= 0) ? wa[id] : 0.f;
  }
  __syncthreads();

  const int l = tid & 63, w = tid >> 6;
  const size_t kbase = (size_t)kh * 2048;
  const u16* aps[4]; const u16* bps[4];
  u16* ald[4]; u16* bld[4];
#pragma unroll
  for (int q = 0; q < 4; ++q) {
    int ra = 32 * w + 8 * q + (l >> 3);
    int id = rowid[ra];
    aps[q] = H + (size_t)(id < 0 ? 0 : id) * 4096 + kbase + ((l & 7) ^ (ra & 7)) * 8;
    ald[q] = As + (32 * w + 8 * q) * 64;
    int rb = 32 * w + 8 * q + (l >> 3);
    int nt = (n0 >> 6) + (rb >> 6);
    bps[q] = w2t + (((size_t)e * 16 + nt) * 64 + kh * 32) * 4096 + (rb & 63) * 64 + ((l & 7) ^ (rb & 7)) * 8;
    bld[q] = Bs + (32 * w + 8 * q) * 64;
  }

  const int wm = (w >> 1) * 64, wn = (w & 1) * 64;
  const int l15 = l & 15, lg = l >> 4;

  f32x4 acc[4][4];
  const f32x4 zf = {0.f, 0.f, 0.f, 0.f};
#pragma unroll
  for (int mi = 0; mi < 4; ++mi)
#pragma unroll
    for (int ni = 0; ni < 4; ++ni) acc[mi][ni] = zf;

  for (int kt = 0; kt < 32; ++kt) {
#pragma unroll
    for (int q = 0; q < 4; ++q) GLL16(aps[q] + kt * 64, ald[q]);
#pragma unroll
    for (int q = 0; q < 4; ++q) GLL16(bps[q] + kt * 4096, bld[q]);
    __syncthreads();
#pragma unroll
    for (int ks = 0; ks < 2; ++ks) {
      const int kb = ks * 64 + lg * 16;
      bf16x8 af[4];
#pragma unroll
      for (int mi = 0; mi < 4; ++mi)
        af[mi] = *(const bf16x8*)lds_swz(As, wm + mi * 16 + l15, kb);
#pragma unroll
      for (int ni = 0; ni < 4; ++ni) {
        bf16x8 bfb = *(const bf16x8*)lds_swz(Bs, wn + ni * 16 + l15, kb);
#pragma unroll
        for (int mi = 0; mi < 4; ++mi)
          acc[mi][ni] = __builtin_amdgcn_mfma_f32_16x16x32_bf16(af[mi], bfb, acc[mi][ni], 0, 0, 0);
      }
    }
    __syncthreads();
  }

#pragma unroll
  for (int mi = 0; mi < 4; ++mi) {
    const int rb = wm + mi * 16 + lg * 4;
#pragma unroll
    for (int ni = 0; ni < 4; ++ni) {
      const int col = n0 + wn + ni * 16 + l15;
      f32x4 c = acc[mi][ni];
#pragma unroll
      for (int j = 0; j < 4; ++j) {
        int rr = rb + j;
        int id = rowid[rr];
        if (id >= 0)
          unsafeAtomicAdd(&out[(size_t)(id >> 1) * 1024 + col], c[j] * rw[rr]);
      }
    }
  }
}

extern "C" void kernel_launch(void* const* d_in, const int* in_sizes, int n_in,
                              void* d_out, int out_size, void* d_ws, size_t ws_size,
                              hipStream_t stream)
{
  (void)in_sizes; (void)n_in; (void)out_size; (void)ws_size;
  const float* x  = (const float*)d_in[0];
  const float* gw = (const float*)d_in[1];
  const float* w1 = (const float*)d_in[2];
  const float* w3 = (const float*)d_in[3];
  const float* w2 = (const float*)d_in[4];
  float* out   = (float*)d_out;
  float* probs = out + (size_t)4096 * 1024;

  const size_t MB = (size_t)1 << 20;
  char* ws = (char*)d_ws;
  u16*   xb    = (u16*)(ws);
  u16*   H     = (u16*)(ws + 8 * MB);
  u16*   w2t   = (u16*)(ws + 200 * MB);
  float* wa    = (float*)(ws + 264 * MB);
  int*   alist = (int*)(ws + 264 * MB + 32768);
  int*   cnt   = (int*)(ws + 264 * MB + 32768 + 131072);

  (void)hipMemsetAsync(cnt, 0, 8 * sizeof(int), stream);
  (void)hipMemsetAsync(out, 0, (size_t)4096 * 1024 * sizeof(float), stream);
  router_k<<<4096, 256, 0, stream>>>(x, gw, probs, xb, wa, alist, cnt);
  gemm1w2_k<<<dim3(80, 32, 8), 256, 0, stream>>>(xb, w1, w3, alist, cnt, H, w2, w2t);
  gemm2_k<<<dim3(8, 64, 8), 256, 0, stream>>>(H, w2t, alist, cnt, wa, out);
}

// Round 12
// 513.879 us; speedup vs baseline: 1.0190x; 1.0190x over previous
//
#include <hip/hip_runtime.h>

typedef unsigned short u16;
typedef unsigned int u32;
typedef __attribute__((ext_vector_type(8))) short bf16x8;
typedef __attribute__((ext_vector_type(4))) float f32x4;
typedef __attribute__((ext_vector_type(4))) int i32x4;
typedef __attribute__((ext_vector_type(2))) unsigned int u32x2;

// T=4096 tokens, D=1024, F=4096, E=8, K=2. Inputs fp32.
// ws: xb(8M) | H(64M) | w1t(64M) | w3t(64M) | w2t(64M) | wa/alist/cnt
// DAG: L1 = router + prep w1/w3 e0-3; L2a = gemm1(e0-3) + prep w1/w3 e4-7;
//      L2b = gemm1(e4-7) + prep w2(all); L3 = gemm2.

__device__ __forceinline__ u16 f2bf(float f) {
  u32 u = __builtin_bit_cast(u32, f);
  u += 0x7fffu + ((u >> 16) & 1u);
  return (u16)(u >> 16);
}
__device__ __forceinline__ u32 pack2(u16 a, u16 b) { return (u32)a | ((u32)b << 16); }

// XOR-swizzled LDS byte address for [row][64 bf16] GEMM tiles (128B rows); 16B-unit swizzle.
__device__ __forceinline__ char* lds_swz(void* base, int row, int byteInRow) {
  return (char*)base + (((row << 7) + byteInRow) ^ ((row & 7) << 4));
}

// async global->LDS, 16B per lane; LDS dest = wave-uniform base + lane*16, global src per-lane.
#define GLL16(g, l) __builtin_amdgcn_global_load_lds( \
    (const __attribute__((address_space(1))) void*)(g), \
    (__attribute__((address_space(3))) void*)(l), 16, 0, 0)

// ---- 256(src rows) x 64(src cols) fp32->bf16 transpose tile (R5-proven) ----
__device__ __forceinline__ void wtrans256_tile(const float* __restrict__ src, u16* __restrict__ dst,
                                               int R, int C, int c0, int r0, void* lds)
{
  char* t = (char*)lds;
  const int tid = threadIdx.x;
  const int rr = (tid >> 4) * 4;
  const int cc = (tid & 15) * 4;
#pragma unroll
  for (int rp = 0; rp < 4; ++rp) {
    f32x4 v[4];
#pragma unroll
    for (int j = 0; j < 4; ++j)
      v[j] = *(const f32x4*)(src + (size_t)(r0 + rp * 64 + rr + j) * C + c0 + cc);
#pragma unroll
    for (int c = 0; c < 4; ++c) {
      u32x2 p;
      p[0] = pack2(f2bf(v[0][c]), f2bf(v[1][c]));
      p[1] = pack2(f2bf(v[2][c]), f2bf(v[3][c]));
      const int col = cc + c;
      const int rowb = (rp * 64 + rr) * 2;
      *(u32x2*)(t + col * 528 + (rowb ^ (((col >> 2) & 7) << 4))) = p;
    }
  }
  __syncthreads();
  const int c = tid >> 2;
  const int ch = (tid & 3) * 128;
  u16* dp = dst + (size_t)(c0 + c) * R + r0;
  const int sw = ((c >> 2) & 7) << 4;
#pragma unroll
  for (int k = 0; k < 8; ++k) {
    i32x4 a = *(const i32x4*)(t + c * 528 + ((ch + k * 16) ^ sw));
    *(i32x4*)((char*)dp + ch + k * 16) = a;
  }
}

// ---------------- L1: router + w1/w3 prep experts 0-3 ----------------
__global__ __launch_bounds__(256) void l1_k(
    const float* __restrict__ w1, const float* __restrict__ w3,
    u16* __restrict__ w1t, u16* __restrict__ w3t,
    const float* __restrict__ x, const float* __restrict__ gw,
    float* __restrict__ probs, u16* __restrict__ xb,
    float* __restrict__ wa, int* __restrict__ alist, int* __restrict__ cnt)
{
  __shared__ __align__(16) char smem[33792];
  const int bid = blockIdx.x;
  if (bid >= 4096) {
    const int t0 = bid - 4096;          // 0..2047
    const int sel = t0 >> 10;           // 0:w1 1:w3
    const int rem = t0 & 1023;
    const int e = rem >> 8;             // 0..3
    const int idx = rem & 255;
    const int rt = idx >> 6, ct = idx & 63;
    const float* src = (sel ? w3 : w1) + (size_t)e * 4194304;
    u16* dst = (sel ? w3t : w1t) + (size_t)e * 4194304;
    wtrans256_tile(src, dst, 1024, 4096, ct * 64, rt * 256, smem);
    return;
  }
  // ---- router block
  const int t = bid;
  const int tid = threadIdx.x;
  f32x4 xv = ((const f32x4*)(x + (size_t)t * 1024))[tid];
  u32x2 hb;
  hb[0] = pack2(f2bf(xv[0]), f2bf(xv[1]));
  hb[1] = pack2(f2bf(xv[2]), f2bf(xv[3]));
  *(u32x2*)(xb + (size_t)t * 1024 + tid * 4) = hb;

  float acc[8];
#pragma unroll
  for (int e = 0; e < 8; ++e) acc[e] = 0.f;
  const float* g = gw + tid * 32;
#pragma unroll
  for (int j = 0; j < 4; ++j)
#pragma unroll
    for (int e = 0; e < 8; ++e) acc[e] = fmaf(xv[j], g[j * 8 + e], acc[e]);

#pragma unroll
  for (int e = 0; e < 8; ++e)
    for (int off = 32; off > 0; off >>= 1) acc[e] += __shfl_down(acc[e], off);

  float* red = (float*)smem;
  const int lane = tid & 63, wid = tid >> 6;
  if (lane == 0) {
#pragma unroll
    for (int e = 0; e < 8; ++e) red[wid * 8 + e] = acc[e];
  }
  __syncthreads();
  if (tid == 0) {
    float p[8]; float mx = -1e30f;
#pragma unroll
    for (int e = 0; e < 8; ++e) { p[e] = red[e] + red[8 + e] + red[16 + e] + red[24 + e]; mx = fmaxf(mx, p[e]); }
    float s = 0.f;
#pragma unroll
    for (int e = 0; e < 8; ++e) { p[e] = __expf(p[e] - mx); s += p[e]; }
    float inv = 1.f / s;
#pragma unroll
    for (int e = 0; e < 8; ++e) { p[e] *= inv; probs[(size_t)t * 8 + e] = p[e]; }
    int i0 = 0;
#pragma unroll
    for (int e = 1; e < 8; ++e) if (p[e] > p[i0]) i0 = e;
    int i1 = (i0 == 0) ? 1 : 0;
#pragma unroll
    for (int e = 0; e < 8; ++e) if (e != i0 && p[e] > p[i1]) i1 = e;
    float s2 = p[i0] + p[i1];
    int pos0 = atomicAdd(&cnt[i0], 1); alist[i0 * 4096 + pos0] = t * 2;
    int pos1 = atomicAdd(&cnt[i1], 1); alist[i1 * 4096 + pos1] = t * 2 + 1;
    wa[t * 2]     = p[i0] / s2;
    wa[t * 2 + 1] = p[i1] / s2;
  }
}

// ---- gemm1 block body (R5-proven): tile 128M x (64+64)N for expert e ----
__device__ __forceinline__ void gemm1_body(
    char* smem, const u16* __restrict__ xb, const u16* __restrict__ w1t, const u16* __restrict__ w3t,
    const int* __restrict__ alist, const int* __restrict__ cnt, u16* __restrict__ H, int e)
{
  u16* As = (u16*)smem;                  // [128*64]
  u16* Bs = (u16*)(smem + 16384);        // [2][64*64]
  int* rowid = (int*)(smem + 32768);     // [128]

  const int mc = cnt[e];
  const int m0 = blockIdx.y * 128;
  if (m0 >= mc) return;
  const int n0 = blockIdx.x * 64;
  const int tid = threadIdx.x;

  if (tid < 128) rowid[tid] = (m0 + tid < mc) ? alist[e * 4096 + m0 + tid] : -1;
  __syncthreads();

  const int l = tid & 63, w = tid >> 6;
  const u16* wt = (w >> 1) ? w3t : w1t;
  u16* bbase = Bs + (w >> 1) * 4096;

  const u16* aps[4]; const u16* bps[4];
  u16* ald[4]; u16* bld[4];
#pragma unroll
  for (int q = 0; q < 4; ++q) {
    int ra = 32 * w + 8 * q + (l >> 3);
    int id = rowid[ra];
    aps[q] = xb + (size_t)(id < 0 ? 0 : (id >> 1)) * 1024 + ((l & 7) ^ (ra & 7)) * 8;
    ald[q] = As + (32 * w + 8 * q) * 64;
    int rb = 32 * (w & 1) + 8 * q + (l >> 3);
    bps[q] = wt + (size_t)e * 4194304 + (size_t)(n0 + rb) * 1024 + ((l & 7) ^ (rb & 7)) * 8;
    bld[q] = bbase + (32 * (w & 1) + 8 * q) * 64;
  }

  const int wm = (w >> 1) * 64, wn = (w & 1) * 32;
  const int l15 = l & 15, lg = l >> 4;

  f32x4 acc1[4][2], acc3[4][2];
  const f32x4 zf = {0.f, 0.f, 0.f, 0.f};
#pragma unroll
  for (int mi = 0; mi < 4; ++mi) { acc1[mi][0] = zf; acc1[mi][1] = zf; acc3[mi][0] = zf; acc3[mi][1] = zf; }

  for (int kt = 0; kt < 16; ++kt) {
    const int ko = kt * 64;
#pragma unroll
    for (int q = 0; q < 4; ++q) GLL16(aps[q] + ko, ald[q]);
#pragma unroll
    for (int q = 0; q < 4; ++q) GLL16(bps[q] + ko, bld[q]);
    __syncthreads();
#pragma unroll
    for (int ks = 0; ks < 2; ++ks) {
      const int kb = ks * 64 + lg * 16;
      bf16x8 af[4];
#pragma unroll
      for (int mi = 0; mi < 4; ++mi)
        af[mi] = *(const bf16x8*)lds_swz(As, wm + mi * 16 + l15, kb);
#pragma unroll
      for (int ni = 0; ni < 2; ++ni) {
        bf16x8 b1 = *(const bf16x8*)lds_swz(Bs, wn + ni * 16 + l15, kb);
        bf16x8 b3 = *(const bf16x8*)lds_swz(Bs + 4096, wn + ni * 16 + l15, kb);
#pragma unroll
        for (int mi = 0; mi < 4; ++mi) {
          acc1[mi][ni] = __builtin_amdgcn_mfma_f32_16x16x32_bf16(af[mi], b1, acc1[mi][ni], 0, 0, 0);
          acc3[mi][ni] = __builtin_amdgcn_mfma_f32_16x16x32_bf16(af[mi], b3, acc3[mi][ni], 0, 0, 0);
        }
      }
    }
    __syncthreads();
  }

#pragma unroll
  for (int mi = 0; mi < 4; ++mi) {
    const int rb = wm + mi * 16 + lg * 4;
#pragma unroll
    for (int ni = 0; ni < 2; ++ni) {
      const int col = blockIdx.x * 64 + wn + ni * 16 + l15;
      f32x4 c1 = acc1[mi][ni], c3 = acc3[mi][ni];
#pragma unroll
      for (int j = 0; j < 4; ++j) {
        int id = rowid[rb + j];
        if (id >= 0) {
          float a = c1[j];
          float h = (a / (1.f + __expf(-a))) * c3[j];
          H[(size_t)id * 4096 + col] = f2bf(h);
        }
      }
    }
  }
}

// ---------------- L2a: gemm1 e0-3 + w1/w3 prep e4-7 overlaid ----------------
__global__ __launch_bounds__(256, 2) void l2a_k(
    const u16* __restrict__ xb, const u16* __restrict__ w1t, const u16* __restrict__ w3t,
    const int* __restrict__ alist, const int* __restrict__ cnt, u16* __restrict__ H,
    const float* __restrict__ w1, const float* __restrict__ w3,
    u16* __restrict__ w1to, u16* __restrict__ w3to)
{
  __shared__ __align__(16) char smem[33792];
  const int bx = blockIdx.x;
  if (bx >= 64) {
    const int slot = ((bx - 64) * 32 + blockIdx.y) * 4 + blockIdx.z;  // 0..2047
    const int sel = slot >> 10;
    const int r = slot & 1023;
    const int e2 = 4 + (r >> 8);        // 4..7
    const int idx = r & 255;
    const int rt = idx >> 6, ct = idx & 63;
    const float* src = (sel ? w3 : w1) + (size_t)e2 * 4194304;
    u16* dst = (sel ? w3to : w1to) + (size_t)e2 * 4194304;
    wtrans256_tile(src, dst, 1024, 4096, ct * 64, rt * 256, smem);
    return;
  }
  gemm1_body(smem, xb, w1t, w3t, alist, cnt, H, blockIdx.z);
}

// ---------------- L2b: gemm1 e4-7 + w2 prep (all experts) overlaid ----------------
__global__ __launch_bounds__(256, 2) void l2b_k(
    const u16* __restrict__ xb, const u16* __restrict__ w1t, const u16* __restrict__ w3t,
    const int* __restrict__ alist, const int* __restrict__ cnt, u16* __restrict__ H,
    const float* __restrict__ w2, u16* __restrict__ w2t)
{
  __shared__ __align__(16) char smem[33792];
  const int bx = blockIdx.x;
  if (bx >= 64) {
    const int slot = ((bx - 64) * 32 + blockIdx.y) * 4 + blockIdx.z;  // 0..2047
    const int e2 = slot >> 8;           // 0..7
    const int idx = slot & 255;
    const int rt = idx >> 4, ct = idx & 15;
    const float* src = w2 + (size_t)e2 * 4194304;
    u16* dst = w2t + (size_t)e2 * 4194304;
    wtrans256_tile(src, dst, 4096, 1024, ct * 64, rt * 256, smem);
    return;
  }
  gemm1_body(smem, xb, w1t, w3t, alist, cnt, H, blockIdx.z + 4);
}

// ---------------- gemm2 (R5-proven): out[token] += wa * (H @ w2), split-K=2, fused combine ----------------
__global__ __launch_bounds__(256, 2) void gemm2_k(
    const u16* __restrict__ H, const u16* __restrict__ w2t,
    const int* __restrict__ alist, const int* __restrict__ cnt,
    const float* __restrict__ wa, float* __restrict__ out)
{
  const int e = blockIdx.z;
  const int mc = cnt[e];
  const int yy = blockIdx.y;
  const int kh = yy & 1;
  const int m0 = (yy >> 1) * 128;
  if (m0 >= mc) return;
  const int n0 = blockIdx.x * 128;
  const int tid = threadIdx.x;

  __shared__ u16 As[128 * 64];
  __shared__ u16 Bs[128 * 64];
  __shared__ int rowid[128];
  __shared__ float rw[128];

  if (tid < 128) {
    int id = (m0 + tid < mc) ? alist[e * 4096 + m0 + tid] : -1;
    rowid[tid] = id;
    rw[tid] = (id >= 0) ? wa[id] : 0.f;
  }
  __syncthreads();

  const int l = tid & 63, w = tid >> 6;
  const size_t kbase = (size_t)kh * 2048;
  const u16* aps[4]; const u16* bps[4];
  u16* ald[4]; u16* bld[4];
#pragma unroll
  for (int q = 0; q < 4; ++q) {
    int ra = 32 * w + 8 * q + (l >> 3);
    int id = rowid[ra];
    aps[q] = H + (size_t)(id < 0 ? 0 : id) * 4096 + kbase + ((l & 7) ^ (ra & 7)) * 8;
    ald[q] = As + (32 * w + 8 * q) * 64;
    int rb = 32 * w + 8 * q + (l >> 3);
    bps[q] = w2t + (size_t)e * 4194304 + (size_t)(n0 + rb) * 4096 + kbase + ((l & 7) ^ (rb & 7)) * 8;
    bld[q] = Bs + (32 * w + 8 * q) * 64;
  }

  const int wm = (w >> 1) * 64, wn = (w & 1) * 64;
  const int l15 = l & 15, lg = l >> 4;

  f32x4 acc[4][4];
  const f32x4 zf = {0.f, 0.f, 0.f, 0.f};
#pragma unroll
  for (int mi = 0; mi < 4; ++mi)
#pragma unroll
    for (int ni = 0; ni < 4; ++ni) acc[mi][ni] = zf;

  for (int kt = 0; kt < 32; ++kt) {
    const int ko = kt * 64;
#pragma unroll
    for (int q = 0; q < 4; ++q) GLL16(aps[q] + ko, ald[q]);
#pragma unroll
    for (int q = 0; q < 4; ++q) GLL16(bps[q] + ko, bld[q]);
    __syncthreads();
#pragma unroll
    for (int ks = 0; ks < 2; ++ks) {
      const int kb = ks * 64 + lg * 16;
      bf16x8 af[4];
#pragma unroll
      for (int mi = 0; mi < 4; ++mi)
        af[mi] = *(const bf16x8*)lds_swz(As, wm + mi * 16 + l15, kb);
#pragma unroll
      for (int ni = 0; ni < 4; ++ni) {
        bf16x8 bfb = *(const bf16x8*)lds_swz(Bs, wn + ni * 16 + l15, kb);
#pragma unroll
        for (int mi = 0; mi < 4; ++mi)
          acc[mi][ni] = __builtin_amdgcn_mfma_f32_16x16x32_bf16(af[mi], bfb, acc[mi][ni], 0, 0, 0);
      }
    }
    __syncthreads();
  }

#pragma unroll
  for (int mi = 0; mi < 4; ++mi) {
    const int rb = wm + mi * 16 + lg * 4;
#pragma unroll
    for (int ni = 0; ni < 4; ++ni) {
      const int col = n0 + wn + ni * 16 + l15;
      f32x4 c = acc[mi][ni];
#pragma unroll
      for (int j = 0; j < 4; ++j) {
        int rr = rb + j;
        int id = rowid[rr];
        if (id >= 0)
          unsafeAtomicAdd(&out[(size_t)(id >> 1) * 1024 + col], c[j] * rw[rr]);
      }
    }
  }
}

extern "C" void kernel_launch(void* const* d_in, const int* in_sizes, int n_in,
                              void* d_out, int out_size, void* d_ws, size_t ws_size,
                              hipStream_t stream)
{
  (void)in_sizes; (void)n_in; (void)out_size; (void)ws_size;
  const float* x  = (const float*)d_in[0];
  const float* gw = (const float*)d_in[1];
  const float* w1 = (const float*)d_in[2];
  const float* w3 = (const float*)d_in[3];
  const float* w2 = (const float*)d_in[4];
  float* out   = (float*)d_out;
  float* probs = out + (size_t)4096 * 1024;

  const size_t MB = (size_t)1 << 20;
  char* ws = (char*)d_ws;
  u16*   xb    = (u16*)(ws);
  u16*   H     = (u16*)(ws + 8 * MB);
  u16*   w1t   = (u16*)(ws + 72 * MB);
  u16*   w3t   = (u16*)(ws + 136 * MB);
  u16*   w2t   = (u16*)(ws + 200 * MB);
  float* wa    = (float*)(ws + 264 * MB);
  int*   alist = (int*)(ws + 264 * MB + 32768);
  int*   cnt   = (int*)(ws + 264 * MB + 32768 + 131072);

  (void)hipMemsetAsync(cnt, 0, 8 * sizeof(int), stream);
  (void)hipMemsetAsync(out, 0, (size_t)4096 * 1024 * sizeof(float), stream);
  l1_k<<<6144, 256, 0, stream>>>(w1, w3, w1t, w3t, x, gw, probs, xb, wa, alist, cnt);
  l2a_k<<<dim3(80, 32, 4), 256, 0, stream>>>(xb, w1t, w3t, alist, cnt, H, w1, w3, w1t, w3t);
  l2b_k<<<dim3(80, 32, 4), 256, 0, stream>>>(xb, w1t, w3t, alist, cnt, H, w2, w2t);
  gemm2_k<<<dim3(8, 64, 8), 256, 0, stream>>>(H, w2t, alist, cnt, wa, out);
}

// Round 13
// 432.116 us; speedup vs baseline: 1.2119x; 1.1892x over previous
//
#include <hip/hip_runtime.h>

typedef unsigned short u16;
typedef unsigned int u32;
typedef __attribute__((ext_vector_type(8))) short bf16x8;
typedef __attribute__((ext_vector_type(4))) float f32x4;
typedef __attribute__((ext_vector_type(4))) int i32x4;
typedef __attribute__((ext_vector_type(2))) unsigned int u32x2;

// T=4096 tokens, D=1024, F=4096, E=8, K=2. Inputs fp32.
// ws: xb(8M) | H(64M) | w1t(64M) | w3t(64M) | w2t(64M) | wa/alist/cnt

__device__ __forceinline__ u16 f2bf(float f) {
  u32 u = __builtin_bit_cast(u32, f);
  u += 0x7fffu + ((u >> 16) & 1u);
  return (u16)(u >> 16);
}
__device__ __forceinline__ u32 pack2(u16 a, u16 b) { return (u32)a | ((u32)b << 16); }
__device__ __forceinline__ u32 cvt2(float a, float b) { return pack2(f2bf(a), f2bf(b)); }

// XOR-swizzled LDS byte address for [row][64 bf16] GEMM tiles (128B rows); 16B-unit swizzle.
__device__ __forceinline__ char* lds_swz(void* base, int row, int byteInRow) {
  return (char*)base + (((row << 7) + byteInRow) ^ ((row & 7) << 4));
}

// async global->LDS, 16B per lane; LDS dest = wave-uniform base + lane*16, global src per-lane.
#define GLL16(g, l) __builtin_amdgcn_global_load_lds( \
    (const __attribute__((address_space(1))) void*)(g), \
    (__attribute__((address_space(3))) void*)(l), 16, 0, 0)

// ---- 64x64 fp32->bf16 transpose tile helper (uses caller's LDS) ----
__device__ __forceinline__ void wtrans_tile(const float* __restrict__ src, u16* __restrict__ dst,
                                            int R, int C, int c0, int r0, void* lds)
{
  u16 (*t)[72] = (u16 (*)[72])lds;
  const int tid = threadIdx.x;
  const int rr = (tid >> 4) * 4, cc = (tid & 15) * 4;
  f32x4 v[4];
#pragma unroll
  for (int j = 0; j < 4; ++j) v[j] = *(const f32x4*)(src + (size_t)(r0 + rr + j) * C + c0 + cc);
#pragma unroll
  for (int c = 0; c < 4; ++c) {
    u32x2 p;
    p[0] = pack2(f2bf(v[0][c]), f2bf(v[1][c]));
    p[1] = pack2(f2bf(v[2][c]), f2bf(v[3][c]));
    *(u32x2*)&t[cc + c][rr] = p;
  }
  __syncthreads();
  const int c = tid >> 2, rs = (tid & 3) * 16;
  i32x4 a0 = *(const i32x4*)&t[c][rs];
  i32x4 a1 = *(const i32x4*)&t[c][rs + 8];
  u16* dp = dst + (size_t)(c0 + c) * R + r0 + rs;
  *(i32x4*)dp = a0;
  *(i32x4*)(dp + 8) = a1;
}

// ---------------- router v2: 128 blocks x 32 tokens, block-aggregated atomics ----------------
__global__ __launch_bounds__(256) void router2_k(
    const float* __restrict__ x, const float* __restrict__ gw,
    float* __restrict__ probs, u16* __restrict__ xb,
    float* __restrict__ wa, int* __restrict__ alist, int* __restrict__ cnt)
{
  const int tid = threadIdx.x;
  const int wv = tid >> 6, l = tid & 63;
  const int tb = blockIdx.x * 32;

  __shared__ int lcnt[8];
  __shared__ int gbase[8];
  __shared__ int s_e[64];
  __shared__ int s_pos[64];
  __shared__ int s_row[64];

  if (tid < 8) lcnt[tid] = 0;
  __syncthreads();

  for (int i = 0; i < 8; ++i) {
    const int t = tb + wv * 8 + i;
    const float* xrow = x + (size_t)t * 1024;
    f32x4 xv[4];
#pragma unroll
    for (int j = 0; j < 4; ++j) xv[j] = *(const f32x4*)(xrow + j * 256 + l * 4);

    // x -> bf16 (interleaved layout matches source d = j*256 + l*4 + c)
    u16* xbt = xb + (size_t)t * 1024;
#pragma unroll
    for (int j = 0; j < 4; ++j) {
      u32x2 hb;
      hb[0] = cvt2(xv[j][0], xv[j][1]);
      hb[1] = cvt2(xv[j][2], xv[j][3]);
      *(u32x2*)(xbt + j * 256 + l * 4) = hb;
    }

    float acc[8];
#pragma unroll
    for (int e = 0; e < 8; ++e) acc[e] = 0.f;
#pragma unroll
    for (int j = 0; j < 4; ++j) {
      const float* g = gw + j * 2048 + l * 32;
#pragma unroll
      for (int c = 0; c < 4; ++c)
#pragma unroll
        for (int e = 0; e < 8; ++e) acc[e] = fmaf(xv[j][c], g[c * 8 + e], acc[e]);
    }
#pragma unroll
    for (int e = 0; e < 8; ++e)
      for (int off = 32; off > 0; off >>= 1) acc[e] += __shfl_down(acc[e], off);

    if (l == 0) {
      float p[8]; float mx = -1e30f;
#pragma unroll
      for (int e = 0; e < 8; ++e) { p[e] = acc[e]; mx = fmaxf(mx, p[e]); }
      float s = 0.f;
#pragma unroll
      for (int e = 0; e < 8; ++e) { p[e] = __expf(p[e] - mx); s += p[e]; }
      float inv = 1.f / s;
#pragma unroll
      for (int e = 0; e < 8; ++e) { p[e] *= inv; probs[(size_t)t * 8 + e] = p[e]; }
      int i0 = 0;
#pragma unroll
      for (int e = 1; e < 8; ++e) if (p[e] > p[i0]) i0 = e;
      int i1 = (i0 == 0) ? 1 : 0;
#pragma unroll
      for (int e = 0; e < 8; ++e) if (e != i0 && p[e] > p[i1]) i1 = e;
      float s2 = p[i0] + p[i1];
      int p0 = atomicAdd(&lcnt[i0], 1);
      int p1 = atomicAdd(&lcnt[i1], 1);
      const int si = (wv * 8 + i) * 2;
      s_e[si] = i0;   s_pos[si] = p0;   s_row[si] = t * 2;
      s_e[si+1] = i1; s_pos[si+1] = p1; s_row[si+1] = t * 2 + 1;
      wa[t * 2]     = p[i0] / s2;
      wa[t * 2 + 1] = p[i1] / s2;
    }
  }
  __syncthreads();
  if (tid < 8) gbase[tid] = atomicAdd(&cnt[tid], lcnt[tid]);   // 8 global atomics / block
  __syncthreads();
  if (tid < 64) {
    int e = s_e[tid];
    alist[e * 4096 + gbase[e] + s_pos[tid]] = s_row[tid];
  }
}

// ---------------- prep13: w1/w3 fp32 -> bf16 transposed (standalone, for visibility) ----------------
__global__ __launch_bounds__(256) void prep13_k(
    const float* __restrict__ w1, const float* __restrict__ w3,
    u16* __restrict__ w1t, u16* __restrict__ w3t)
{
  __shared__ __align__(16) char smem[9216];
  const int bid = blockIdx.x;              // 0..16383
  const int sel = bid >> 13;
  const int t0 = bid & 8191;
  const int e = t0 >> 10;
  const int rem = t0 & 1023;
  const int xt = rem & 63, yt = rem >> 6;
  const float* src = (sel ? w3 : w1) + (size_t)e * 4194304;
  u16* dst = (sel ? w3t : w1t) + (size_t)e * 4194304;
  wtrans_tile(src, dst, 1024, 4096, xt * 64, yt * 64, smem);
}

// ---------------- gemm1 + w2 transpose overlaid (485-build verbatim) ----------------
__global__ __launch_bounds__(256, 2) void gemm1w2_k(
    const u16* __restrict__ xb, const u16* __restrict__ w1t, const u16* __restrict__ w3t,
    const int* __restrict__ alist, const int* __restrict__ cnt, u16* __restrict__ H,
    const float* __restrict__ w2, u16* __restrict__ w2t)
{
  __shared__ __align__(16) char smem[33280];
  const int e = blockIdx.z;
  const int bx = blockIdx.x;

  if (bx >= 64) {
    const float* src = w2 + (size_t)e * 4194304;
    u16* dst = w2t + (size_t)e * 4194304;
    const int slot = (bx - 64) * 32 + blockIdx.y;   // 0..255
#pragma unroll
    for (int j = 0; j < 4; ++j) {
      const int tj = slot * 4 + j;                  // 0..1023
      const int cx = tj & 15, ry = tj >> 4;
      wtrans_tile(src, dst, 4096, 1024, cx * 64, ry * 64, smem);
      __syncthreads();
    }
    return;
  }

  u16* As = (u16*)smem;                  // [128*64]
  u16* Bs = (u16*)(smem + 16384);        // [2][64*64]
  int* rowid = (int*)(smem + 32768);     // [128]

  const int mc = cnt[e];
  const int m0 = blockIdx.y * 128;
  if (m0 >= mc) return;
  const int n0 = bx * 64;
  const int tid = threadIdx.x;

  if (tid < 128) rowid[tid] = (m0 + tid < mc) ? alist[e * 4096 + m0 + tid] : -1;
  __syncthreads();

  const int l = tid & 63, w = tid >> 6;
  const u16* wt = (w >> 1) ? w3t : w1t;
  u16* bbase = Bs + (w >> 1) * 4096;

  const u16* aps[4]; const u16* bps[4];
  u16* ald[4]; u16* bld[4];
#pragma unroll
  for (int q = 0; q < 4; ++q) {
    int ra = 32 * w + 8 * q + (l >> 3);
    int id = rowid[ra];
    aps[q] = xb + (size_t)(id < 0 ? 0 : (id >> 1)) * 1024 + ((l & 7) ^ (ra & 7)) * 8;
    ald[q] = As + (32 * w + 8 * q) * 64;
    int rb = 32 * (w & 1) + 8 * q + (l >> 3);
    bps[q] = wt + (size_t)e * 4194304 + (size_t)(n0 + rb) * 1024 + ((l & 7) ^ (rb & 7)) * 8;
    bld[q] = bbase + (32 * (w & 1) + 8 * q) * 64;
  }

  const int wm = (w >> 1) * 64, wn = (w & 1) * 32;
  const int l15 = l & 15, lg = l >> 4;

  f32x4 acc1[4][2], acc3[4][2];
  const f32x4 zf = {0.f, 0.f, 0.f, 0.f};
#pragma unroll
  for (int mi = 0; mi < 4; ++mi) { acc1[mi][0] = zf; acc1[mi][1] = zf; acc3[mi][0] = zf; acc3[mi][1] = zf; }

  for (int kt = 0; kt < 16; ++kt) {
    const int ko = kt * 64;
#pragma unroll
    for (int q = 0; q < 4; ++q) GLL16(aps[q] + ko, ald[q]);
#pragma unroll
    for (int q = 0; q < 4; ++q) GLL16(bps[q] + ko, bld[q]);
    __syncthreads();
#pragma unroll
    for (int ks = 0; ks < 2; ++ks) {
      const int kb = ks * 64 + lg * 16;
      bf16x8 af[4];
#pragma unroll
      for (int mi = 0; mi < 4; ++mi)
        af[mi] = *(const bf16x8*)lds_swz(As, wm + mi * 16 + l15, kb);
#pragma unroll
      for (int ni = 0; ni < 2; ++ni) {
        bf16x8 b1 = *(const bf16x8*)lds_swz(Bs, wn + ni * 16 + l15, kb);
        bf16x8 b3 = *(const bf16x8*)lds_swz(Bs + 4096, wn + ni * 16 + l15, kb);
#pragma unroll
        for (int mi = 0; mi < 4; ++mi) {
          acc1[mi][ni] = __builtin_amdgcn_mfma_f32_16x16x32_bf16(af[mi], b1, acc1[mi][ni], 0, 0, 0);
          acc3[mi][ni] = __builtin_amdgcn_mfma_f32_16x16x32_bf16(af[mi], b3, acc3[mi][ni], 0, 0, 0);
        }
      }
    }
    __syncthreads();
  }

#pragma unroll
  for (int mi = 0; mi < 4; ++mi) {
    const int rb = wm + mi * 16 + lg * 4;
#pragma unroll
    for (int ni = 0; ni < 2; ++ni) {
      const int col = n0 + wn + ni * 16 + l15;
      f32x4 c1 = acc1[mi][ni], c3 = acc3[mi][ni];
#pragma unroll
      for (int j = 0; j < 4; ++j) {
        int id = rowid[rb + j];
        if (id >= 0) {
          float a = c1[j];
          float h = (a / (1.f + __expf(-a))) * c3[j];
          H[(size_t)id * 4096 + col] = f2bf(h);
        }
      }
    }
  }
}

// ---------------- gemm2: out[token] += wa * (H @ w2), split-K=2, fused combine (485-build verbatim) ----------------
__global__ __launch_bounds__(256, 2) void gemm2_k(
    const u16* __restrict__ H, const u16* __restrict__ w2t,
    const int* __restrict__ alist, const int* __restrict__ cnt,
    const float* __restrict__ wa, float* __restrict__ out)
{
  const int e = blockIdx.z;
  const int mc = cnt[e];
  const int yy = blockIdx.y;
  const int kh = yy & 1;
  const int m0 = (yy >> 1) * 128;
  if (m0 >= mc) return;
  const int n0 = blockIdx.x * 128;
  const int tid = threadIdx.x;

  __shared__ u16 As[128 * 64];
  __shared__ u16 Bs[128 * 64];
  __shared__ int rowid[128];
  __shared__ float rw[128];

  if (tid < 128) {
    int id = (m0 + tid < mc) ? alist[e * 4096 + m0 + tid] : -1;
    rowid[tid] = id;
    rw[tid] = (id >= 0) ? wa[id] : 0.f;
  }
  __syncthreads();

  const int l = tid & 63, w = tid >> 6;
  const size_t kbase = (size_t)kh * 2048;
  const u16* aps[4]; const u16* bps[4];
  u16* ald[4]; u16* bld[4];
#pragma unroll
  for (int q = 0; q < 4; ++q) {
    int ra = 32 * w + 8 * q + (l >> 3);
    int id = rowid[ra];
    aps[q] = H + (size_t)(id < 0 ? 0 : id) * 4096 + kbase + ((l & 7) ^ (ra & 7)) * 8;
    ald[q] = As + (32 * w + 8 * q) * 64;
    int rb = 32 * w + 8 * q + (l >> 3);
    bps[q] = w2t + (size_t)e * 4194304 + (size_t)(n0 + rb) * 4096 + kbase + ((l & 7) ^ (rb & 7)) * 8;
    bld[q] = Bs + (32 * w + 8 * q) * 64;
  }

  const int wm = (w >> 1) * 64, wn = (w & 1) * 64;
  const int l15 = l & 15, lg = l >> 4;

  f32x4 acc[4][4];
  const f32x4 zf = {0.f, 0.f, 0.f, 0.f};
#pragma unroll
  for (int mi = 0; mi < 4; ++mi)
#pragma unroll
    for (int ni = 0; ni < 4; ++ni) acc[mi][ni] = zf;

  for (int kt = 0; kt < 32; ++kt) {
    const int ko = kt * 64;
#pragma unroll
    for (int q = 0; q < 4; ++q) GLL16(aps[q] + ko, ald[q]);
#pragma unroll
    for (int q = 0; q < 4; ++q) GLL16(bps[q] + ko, bld[q]);
    __syncthreads();
#pragma unroll
    for (int ks = 0; ks < 2; ++ks) {
      const int kb = ks * 64 + lg * 16;
      bf16x8 af[4];
#pragma unroll
      for (int mi = 0; mi < 4; ++mi)
        af[mi] = *(const bf16x8*)lds_swz(As, wm + mi * 16 + l15, kb);
#pragma unroll
      for (int ni = 0; ni < 4; ++ni) {
        bf16x8 bfb = *(const bf16x8*)lds_swz(Bs, wn + ni * 16 + l15, kb);
#pragma unroll
        for (int mi = 0; mi < 4; ++mi)
          acc[mi][ni] = __builtin_amdgcn_mfma_f32_16x16x32_bf16(af[mi], bfb, acc[mi][ni], 0, 0, 0);
      }
    }
    __syncthreads();
  }

#pragma unroll
  for (int mi = 0; mi < 4; ++mi) {
    const int rb = wm + mi * 16 + lg * 4;
#pragma unroll
    for (int ni = 0; ni < 4; ++ni) {
      const int col = n0 + wn + ni * 16 + l15;
      f32x4 c = acc[mi][ni];
#pragma unroll
      for (int j = 0; j < 4; ++j) {
        int rr = rb + j;
        int id = rowid[rr];
        if (id >= 0)
          unsafeAtomicAdd(&out[(size_t)(id >> 1) * 1024 + col], c[j] * rw[rr]);
      }
    }
  }
}

extern "C" void kernel_launch(void* const* d_in, const int* in_sizes, int n_in,
                              void* d_out, int out_size, void* d_ws, size_t ws_size,
                              hipStream_t stream)
{
  (void)in_sizes; (void)n_in; (void)out_size; (void)ws_size;
  const float* x  = (const float*)d_in[0];
  const float* gw = (const float*)d_in[1];
  const float* w1 = (const float*)d_in[2];
  const float* w3 = (const float*)d_in[3];
  const float* w2 = (const float*)d_in[4];
  float* out   = (float*)d_out;
  float* probs = out + (size_t)4096 * 1024;

  const size_t MB = (size_t)1 << 20;
  char* ws = (char*)d_ws;
  u16*   xb    = (u16*)(ws);
  u16*   H     = (u16*)(ws + 8 * MB);
  u16*   w1t   = (u16*)(ws + 72 * MB);
  u16*   w3t   = (u16*)(ws + 136 * MB);
  u16*   w2t   = (u16*)(ws + 200 * MB);
  float* wa    = (float*)(ws + 264 * MB);
  int*   alist = (int*)(ws + 264 * MB + 32768);
  int*   cnt   = (int*)(ws + 264 * MB + 32768 + 131072);

  (void)hipMemsetAsync(cnt, 0, 8 * sizeof(int), stream);
  (void)hipMemsetAsync(out, 0, (size_t)4096 * 1024 * sizeof(float), stream);
  router2_k<<<128, 256, 0, stream>>>(x, gw, probs, xb, wa, alist, cnt);
  prep13_k<<<16384, 256, 0, stream>>>(w1, w3, w1t, w3t);
  gemm1w2_k<<<dim3(72, 32, 8), 256, 0, stream>>>(xb, w1t, w3t, alist, cnt, H, w2, w2t);
  gemm2_k<<<dim3(8, 64, 8), 256, 0, stream>>>(H, w2t, alist, cnt, wa, out);
}

// Round 14
// 431.899 us; speedup vs baseline: 1.2125x; 1.0005x over previous
//
#include <hip/hip_runtime.h>

typedef unsigned short u16;
typedef unsigned int u32;
typedef __attribute__((ext_vector_type(8))) short bf16x8;
typedef __attribute__((ext_vector_type(4))) float f32x4;
typedef __attribute__((ext_vector_type(4))) int i32x4;
typedef __attribute__((ext_vector_type(2))) unsigned int u32x2;

// T=4096 tokens, D=1024, F=4096, E=8, K=2. Inputs fp32.
// ws: xb(8M) | H(64M) | w1t(64M) | w3t(64M) | w2t(64M) | wa/alist/cnt

__device__ __forceinline__ u16 f2bf(float f) {
  u32 u = __builtin_bit_cast(u32, f);
  u += 0x7fffu + ((u >> 16) & 1u);
  return (u16)(u >> 16);
}
__device__ __forceinline__ u32 pack2(u16 a, u16 b) { return (u32)a | ((u32)b << 16); }
__device__ __forceinline__ u32 cvt2(float a, float b) { return pack2(f2bf(a), f2bf(b)); }

// XOR-swizzled LDS byte address for [row][64 bf16] GEMM tiles (128B rows); 16B-unit swizzle.
__device__ __forceinline__ char* lds_swz(void* base, int row, int byteInRow) {
  return (char*)base + (((row << 7) + byteInRow) ^ ((row & 7) << 4));
}

// async global->LDS, 16B per lane; LDS dest = wave-uniform base + lane*16, global src per-lane.
#define GLL16(g, l) __builtin_amdgcn_global_load_lds( \
    (const __attribute__((address_space(1))) void*)(g), \
    (__attribute__((address_space(3))) void*)(l), 16, 0, 0)

// ---- 64x64 fp32->bf16 transpose tile helper (uses caller's LDS) ----
__device__ __forceinline__ void wtrans_tile(const float* __restrict__ src, u16* __restrict__ dst,
                                            int R, int C, int c0, int r0, void* lds)
{
  u16 (*t)[72] = (u16 (*)[72])lds;
  const int tid = threadIdx.x;
  const int rr = (tid >> 4) * 4, cc = (tid & 15) * 4;
  f32x4 v[4];
#pragma unroll
  for (int j = 0; j < 4; ++j) v[j] = *(const f32x4*)(src + (size_t)(r0 + rr + j) * C + c0 + cc);
#pragma unroll
  for (int c = 0; c < 4; ++c) {
    u32x2 p;
    p[0] = pack2(f2bf(v[0][c]), f2bf(v[1][c]));
    p[1] = pack2(f2bf(v[2][c]), f2bf(v[3][c]));
    *(u32x2*)&t[cc + c][rr] = p;
  }
  __syncthreads();
  const int c = tid >> 2, rs = (tid & 3) * 16;
  i32x4 a0 = *(const i32x4*)&t[c][rs];
  i32x4 a1 = *(const i32x4*)&t[c][rs + 8];
  u16* dp = dst + (size_t)(c0 + c) * R + r0 + rs;
  *(i32x4*)dp = a0;
  *(i32x4*)(dp + 8) = a1;
}

// ---------------- launch A: router (blocks 0-127) + w1/w3 transpose (blocks 128+) ----------------
__global__ __launch_bounds__(256) void rp_k(
    const float* __restrict__ x, const float* __restrict__ gw,
    float* __restrict__ probs, u16* __restrict__ xb,
    float* __restrict__ wa, int* __restrict__ alist, int* __restrict__ cnt,
    const float* __restrict__ w1, const float* __restrict__ w3,
    u16* __restrict__ w1t, u16* __restrict__ w3t)
{
  __shared__ __align__(16) char smem[9216];
  const int bid = blockIdx.x;
  const int tid = threadIdx.x;

  if (bid >= 128) {
    const int b2 = bid - 128;              // 0..16383
    const int sel = b2 >> 13;
    const int t0 = b2 & 8191;
    const int e = t0 >> 10;
    const int rem = t0 & 1023;
    const int xt = rem & 63, yt = rem >> 6;
    const float* src = (sel ? w3 : w1) + (size_t)e * 4194304;
    u16* dst = (sel ? w3t : w1t) + (size_t)e * 4194304;
    wtrans_tile(src, dst, 1024, 4096, xt * 64, yt * 64, smem);
    return;
  }

  // ---- router block: 32 tokens, 1 wave/token-slot, 8 global atomics/block
  int* lcnt  = (int*)smem;            // [8]
  int* gbase = lcnt + 8;              // [8]
  int* s_e   = gbase + 8;             // [64]
  int* s_pos = s_e + 64;              // [64]
  int* s_row = s_pos + 64;            // [64]
  float* s_wa = (float*)(s_row + 64); // [64]

  const int wv = tid >> 6, l = tid & 63;
  const int tb = bid * 32;

  if (tid < 8) lcnt[tid] = 0;
  __syncthreads();

  for (int i = 0; i < 8; ++i) {
    const int t = tb + wv * 8 + i;
    const float* xrow = x + (size_t)t * 1024;
    f32x4 xv[4];
#pragma unroll
    for (int j = 0; j < 4; ++j) xv[j] = *(const f32x4*)(xrow + j * 256 + l * 4);

    u16* xbt = xb + (size_t)t * 1024;
#pragma unroll
    for (int j = 0; j < 4; ++j) {
      u32x2 hb;
      hb[0] = cvt2(xv[j][0], xv[j][1]);
      hb[1] = cvt2(xv[j][2], xv[j][3]);
      *(u32x2*)(xbt + j * 256 + l * 4) = hb;
    }

    float acc[8];
#pragma unroll
    for (int e = 0; e < 8; ++e) acc[e] = 0.f;
#pragma unroll
    for (int j = 0; j < 4; ++j) {
      const float* g = gw + j * 2048 + l * 32;
#pragma unroll
      for (int c = 0; c < 4; ++c)
#pragma unroll
        for (int e = 0; e < 8; ++e) acc[e] = fmaf(xv[j][c], g[c * 8 + e], acc[e]);
    }
#pragma unroll
    for (int e = 0; e < 8; ++e)
      for (int off = 32; off > 0; off >>= 1) acc[e] += __shfl_down(acc[e], off);

    if (l == 0) {
      float p[8]; float mx = -1e30f;
#pragma unroll
      for (int e = 0; e < 8; ++e) { p[e] = acc[e]; mx = fmaxf(mx, p[e]); }
      float s = 0.f;
#pragma unroll
      for (int e = 0; e < 8; ++e) { p[e] = __expf(p[e] - mx); s += p[e]; }
      float inv = 1.f / s;
#pragma unroll
      for (int e = 0; e < 8; ++e) { p[e] *= inv; probs[(size_t)t * 8 + e] = p[e]; }
      int i0 = 0;
#pragma unroll
      for (int e = 1; e < 8; ++e) if (p[e] > p[i0]) i0 = e;
      int i1 = (i0 == 0) ? 1 : 0;
#pragma unroll
      for (int e = 0; e < 8; ++e) if (e != i0 && p[e] > p[i1]) i1 = e;
      float s2 = p[i0] + p[i1];
      int p0 = atomicAdd(&lcnt[i0], 1);
      int p1 = atomicAdd(&lcnt[i1], 1);
      const int si = (wv * 8 + i) * 2;
      s_e[si] = i0;   s_pos[si] = p0;   s_row[si] = t * 2;
      s_e[si+1] = i1; s_pos[si+1] = p1; s_row[si+1] = t * 2 + 1;
      wa[t * 2]     = p[i0] / s2;
      wa[t * 2 + 1] = p[i1] / s2;
      (void)s_wa;
    }
  }
  __syncthreads();
  if (tid < 8) gbase[tid] = atomicAdd(&cnt[tid], lcnt[tid]);
  __syncthreads();
  if (tid < 64) {
    int e = s_e[tid];
    alist[e * 4096 + gbase[e] + s_pos[tid]] = s_row[tid];
  }
}

// ---------------- gemm1 + w2 transpose overlaid (432-build verbatim) ----------------
__global__ __launch_bounds__(256, 2) void gemm1w2_k(
    const u16* __restrict__ xb, const u16* __restrict__ w1t, const u16* __restrict__ w3t,
    const int* __restrict__ alist, const int* __restrict__ cnt, u16* __restrict__ H,
    const float* __restrict__ w2, u16* __restrict__ w2t)
{
  __shared__ __align__(16) char smem[33280];
  const int e = blockIdx.z;
  const int bx = blockIdx.x;

  if (bx >= 64) {
    const float* src = w2 + (size_t)e * 4194304;
    u16* dst = w2t + (size_t)e * 4194304;
    const int slot = (bx - 64) * 32 + blockIdx.y;   // 0..255
#pragma unroll
    for (int j = 0; j < 4; ++j) {
      const int tj = slot * 4 + j;                  // 0..1023
      const int cx = tj & 15, ry = tj >> 4;
      wtrans_tile(src, dst, 4096, 1024, cx * 64, ry * 64, smem);
      __syncthreads();
    }
    return;
  }

  u16* As = (u16*)smem;                  // [128*64]
  u16* Bs = (u16*)(smem + 16384);        // [2][64*64]
  int* rowid = (int*)(smem + 32768);     // [128]

  const int mc = cnt[e];
  const int m0 = blockIdx.y * 128;
  if (m0 >= mc) return;
  const int n0 = bx * 64;
  const int tid = threadIdx.x;

  if (tid < 128) rowid[tid] = (m0 + tid < mc) ? alist[e * 4096 + m0 + tid] : -1;
  __syncthreads();

  const int l = tid & 63, w = tid >> 6;
  const u16* wt = (w >> 1) ? w3t : w1t;
  u16* bbase = Bs + (w >> 1) * 4096;

  const u16* aps[4]; const u16* bps[4];
  u16* ald[4]; u16* bld[4];
#pragma unroll
  for (int q = 0; q < 4; ++q) {
    int ra = 32 * w + 8 * q + (l >> 3);
    int id = rowid[ra];
    aps[q] = xb + (size_t)(id < 0 ? 0 : (id >> 1)) * 1024 + ((l & 7) ^ (ra & 7)) * 8;
    ald[q] = As + (32 * w + 8 * q) * 64;
    int rb = 32 * (w & 1) + 8 * q + (l >> 3);
    bps[q] = wt + (size_t)e * 4194304 + (size_t)(n0 + rb) * 1024 + ((l & 7) ^ (rb & 7)) * 8;
    bld[q] = bbase + (32 * (w & 1) + 8 * q) * 64;
  }

  const int wm = (w >> 1) * 64, wn = (w & 1) * 32;
  const int l15 = l & 15, lg = l >> 4;

  f32x4 acc1[4][2], acc3[4][2];
  const f32x4 zf = {0.f, 0.f, 0.f, 0.f};
#pragma unroll
  for (int mi = 0; mi < 4; ++mi) { acc1[mi][0] = zf; acc1[mi][1] = zf; acc3[mi][0] = zf; acc3[mi][1] = zf; }

  for (int kt = 0; kt < 16; ++kt) {
    const int ko = kt * 64;
#pragma unroll
    for (int q = 0; q < 4; ++q) GLL16(aps[q] + ko, ald[q]);
#pragma unroll
    for (int q = 0; q < 4; ++q) GLL16(bps[q] + ko, bld[q]);
    __syncthreads();
#pragma unroll
    for (int ks = 0; ks < 2; ++ks) {
      const int kb = ks * 64 + lg * 16;
      bf16x8 af[4];
#pragma unroll
      for (int mi = 0; mi < 4; ++mi)
        af[mi] = *(const bf16x8*)lds_swz(As, wm + mi * 16 + l15, kb);
#pragma unroll
      for (int ni = 0; ni < 2; ++ni) {
        bf16x8 b1 = *(const bf16x8*)lds_swz(Bs, wn + ni * 16 + l15, kb);
        bf16x8 b3 = *(const bf16x8*)lds_swz(Bs + 4096, wn + ni * 16 + l15, kb);
#pragma unroll
        for (int mi = 0; mi < 4; ++mi) {
          acc1[mi][ni] = __builtin_amdgcn_mfma_f32_16x16x32_bf16(af[mi], b1, acc1[mi][ni], 0, 0, 0);
          acc3[mi][ni] = __builtin_amdgcn_mfma_f32_16x16x32_bf16(af[mi], b3, acc3[mi][ni], 0, 0, 0);
        }
      }
    }
    __syncthreads();
  }

#pragma unroll
  for (int mi = 0; mi < 4; ++mi) {
    const int rb = wm + mi * 16 + lg * 4;
#pragma unroll
    for (int ni = 0; ni < 2; ++ni) {
      const int col = n0 + wn + ni * 16 + l15;
      f32x4 c1 = acc1[mi][ni], c3 = acc3[mi][ni];
#pragma unroll
      for (int j = 0; j < 4; ++j) {
        int id = rowid[rb + j];
        if (id >= 0) {
          float a = c1[j];
          float h = (a / (1.f + __expf(-a))) * c3[j];
          H[(size_t)id * 4096 + col] = f2bf(h);
        }
      }
    }
  }
}

// ---------------- gemm2: out[token] += wa * (H @ w2), split-K=4, fused combine ----------------
__global__ __launch_bounds__(256, 2) void gemm2_k(
    const u16* __restrict__ H, const u16* __restrict__ w2t,
    const int* __restrict__ alist, const int* __restrict__ cnt,
    const float* __restrict__ wa, float* __restrict__ out)
{
  const int e = blockIdx.z;
  const int mc = cnt[e];
  const int yy = blockIdx.y;
  const int kq = yy & 3;                 // K quarter: 1024 each
  const int m0 = (yy >> 2) * 128;
  if (m0 >= mc) return;
  const int n0 = blockIdx.x * 128;
  const int tid = threadIdx.x;

  __shared__ u16 As[128 * 64];
  __shared__ u16 Bs[128 * 64];
  __shared__ int rowid[128];
  __shared__ float rw[128];

  if (tid < 128) {
    int id = (m0 + tid < mc) ? alist[e * 4096 + m0 + tid] : -1;
    rowid[tid] = id;
    rw[tid] = (id >= 0) ? wa[id] : 0.f;
  }
  __syncthreads();

  const int l = tid & 63, w = tid >> 6;
  const size_t kbase = (size_t)kq * 1024;
  const u16* aps[4]; const u16* bps[4];
  u16* ald[4]; u16* bld[4];
#pragma unroll
  for (int q = 0; q < 4; ++q) {
    int ra = 32 * w + 8 * q + (l >> 3);
    int id = rowid[ra];
    aps[q] = H + (size_t)(id < 0 ? 0 : id) * 4096 + kbase + ((l & 7) ^ (ra & 7)) * 8;
    ald[q] = As + (32 * w + 8 * q) * 64;
    int rb = 32 * w + 8 * q + (l >> 3);
    bps[q] = w2t + (size_t)e * 4194304 + (size_t)(n0 + rb) * 4096 + kbase + ((l & 7) ^ (rb & 7)) * 8;
    bld[q] = Bs + (32 * w + 8 * q) * 64;
  }

  const int wm = (w >> 1) * 64, wn = (w & 1) * 64;
  const int l15 = l & 15, lg = l >> 4;

  f32x4 acc[4][4];
  const f32x4 zf = {0.f, 0.f, 0.f, 0.f};
#pragma unroll
  for (int mi = 0; mi < 4; ++mi)
#pragma unroll
    for (int ni = 0; ni < 4; ++ni) acc[mi][ni] = zf;

  for (int kt = 0; kt < 16; ++kt) {
    const int ko = kt * 64;
#pragma unroll
    for (int q = 0; q < 4; ++q) GLL16(aps[q] + ko, ald[q]);
#pragma unroll
    for (int q = 0; q < 4; ++q) GLL16(bps[q] + ko, bld[q]);
    __syncthreads();
#pragma unroll
    for (int ks = 0; ks < 2; ++ks) {
      const int kb = ks * 64 + lg * 16;
      bf16x8 af[4];
#pragma unroll
      for (int mi = 0; mi < 4; ++mi)
        af[mi] = *(const bf16x8*)lds_swz(As, wm + mi * 16 + l15, kb);
#pragma unroll
      for (int ni = 0; ni < 4; ++ni) {
        bf16x8 bfb = *(const bf16x8*)lds_swz(Bs, wn + ni * 16 + l15, kb);
#pragma unroll
        for (int mi = 0; mi < 4; ++mi)
          acc[mi][ni] = __builtin_amdgcn_mfma_f32_16x16x32_bf16(af[mi], bfb, acc[mi][ni], 0, 0, 0);
      }
    }
    __syncthreads();
  }

#pragma unroll
  for (int mi = 0; mi < 4; ++mi) {
    const int rb = wm + mi * 16 + lg * 4;
#pragma unroll
    for (int ni = 0; ni < 4; ++ni) {
      const int col = n0 + wn + ni * 16 + l15;
      f32x4 c = acc[mi][ni];
#pragma unroll
      for (int j = 0; j < 4; ++j) {
        int rr = rb + j;
        int id = rowid[rr];
        if (id >= 0)
          unsafeAtomicAdd(&out[(size_t)(id >> 1) * 1024 + col], c[j] * rw[rr]);
      }
    }
  }
}

extern "C" void kernel_launch(void* const* d_in, const int* in_sizes, int n_in,
                              void* d_out, int out_size, void* d_ws, size_t ws_size,
                              hipStream_t stream)
{
  (void)in_sizes; (void)n_in; (void)out_size; (void)ws_size;
  const float* x  = (const float*)d_in[0];
  const float* gw = (const float*)d_in[1];
  const float* w1 = (const float*)d_in[2];
  const float* w3 = (const float*)d_in[3];
  const float* w2 = (const float*)d_in[4];
  float* out   = (float*)d_out;
  float* probs = out + (size_t)4096 * 1024;

  const size_t MB = (size_t)1 << 20;
  char* ws = (char*)d_ws;
  u16*   xb    = (u16*)(ws);
  u16*   H     = (u16*)(ws + 8 * MB);
  u16*   w1t   = (u16*)(ws + 72 * MB);
  u16*   w3t   = (u16*)(ws + 136 * MB);
  u16*   w2t   = (u16*)(ws + 200 * MB);
  float* wa    = (float*)(ws + 264 * MB);
  int*   alist = (int*)(ws + 264 * MB + 32768);
  int*   cnt   = (int*)(ws + 264 * MB + 32768 + 131072);

  (void)hipMemsetAsync(cnt, 0, 8 * sizeof(int), stream);
  (void)hipMemsetAsync(out, 0, (size_t)4096 * 1024 * sizeof(float), stream);
  rp_k<<<16512, 256, 0, stream>>>(x, gw, probs, xb, wa, alist, cnt, w1, w3, w1t, w3t);
  gemm1w2_k<<<dim3(72, 32, 8), 256, 0, stream>>>(xb, w1t, w3t, alist, cnt, H, w2, w2t);
  gemm2_k<<<dim3(8, 128, 8), 256, 0, stream>>>(H, w2t, alist, cnt, wa, out);
}